// Round 5
// baseline (588.036 us; speedup 1.0000x reference)
//
#include <hip/hip_runtime.h>
#include <stdint.h>

typedef short bf16x8 __attribute__((ext_vector_type(8)));
typedef float f32x4 __attribute__((ext_vector_type(4)));
typedef float f32x16 __attribute__((ext_vector_type(16)));

#define SEQ     2048
#define DM      4096
#define NQH     32
#define NKVH    8
#define DK      128
#define NQKV    6144   // 4096 q + 1024 k + 1024 v

// ---------- helpers ----------
__device__ __forceinline__ unsigned short f2bfb(float f) {
    union { float f; unsigned u; } x; x.f = f;
    unsigned r = x.u + 0x7FFFu + ((x.u >> 16) & 1u);   // RNE
    return (unsigned short)(r >> 16);
}

__device__ __forceinline__ unsigned cvt_pk_bf16(float a, float b) {
    unsigned r;
    asm("v_cvt_pk_bf16_f32 %0, %1, %2" : "=v"(r) : "v"(a), "v"(b));
    return r;
}

#if __has_builtin(__builtin_amdgcn_exp2f)
__device__ __forceinline__ float exp2_fast(float x) { return __builtin_amdgcn_exp2f(x); }
#else
__device__ __forceinline__ float exp2_fast(float x) { return exp2f(x); }
#endif

__device__ __forceinline__ void stage16(const void* g, void* l) {
    __builtin_amdgcn_global_load_lds(
        (const __attribute__((address_space(1))) void*)g,
        (__attribute__((address_space(3))) void*)l,
        16, 0, 0);
}

// ---------- fp32 -> bf16 conversion (vectorized, grid-stride) ----------
__global__ __launch_bounds__(256)
void cvt_bf16(const float4* __restrict__ src, ushort4* __restrict__ dst, int n4) {
    int i = blockIdx.x * 256 + threadIdx.x;
    const int stride = gridDim.x * 256;
    for (; i < n4; i += stride) {
        float4 f = src[i];
        ushort4 u;
        u.x = f2bfb(f.x); u.y = f2bfb(f.y); u.z = f2bfb(f.z); u.w = f2bfb(f.w);
        dst[i] = u;
    }
}

// ---------- GEMM 8-phase: C[M][N] = A[M][K](bf16) * B[N][K](bf16)^T, fp32 out ----------
// BM=256, BN=128, BK=64. 512 threads = 8 waves as 4M x 2N (64x64 per wave).
// LDS: 2 slots x (A[256][64] + B[128][64]) bf16, XOR-swizzled (byte ^= (row&7)<<4),
// staged via global_load_lds from pre-swizzled global source (linear LDS dest).
// Per K-tile: 4 phases {ds_read quadrant -> barrier -> lgkmcnt(0) -> 8 MFMA -> barrier},
// tile t+1 burst-staged in phase 0, single vmcnt(0) at phase-3 end.
__global__ __launch_bounds__(512, 2)
void gemm256(const unsigned short* __restrict__ A, const unsigned short* __restrict__ B,
             float* __restrict__ C, int M, int N, int K)
{
    __shared__ __align__(16) char lds[2 * 49152];   // 96 KiB

    const int tid = threadIdx.x;
    const int w   = tid >> 6;
    const int l   = tid & 63;
    const int lr  = l & 15;
    const int lg  = l >> 4;
    const int wr  = w >> 1;          // 0..3 -> M offset wr*64
    const int wc  = w & 1;           // 0..1 -> N offset wc*64

    // XCD-chunked block swizzle (nwg % 8 == 0 for both our GEMMs)
    const int nbn = N >> 7;
    const int nwg = gridDim.x;
    const int qz  = nwg >> 3;
    const int id  = blockIdx.x;
    const int swz = (id & 7) * qz + (id >> 3);
    const int m0  = (swz / nbn) << 8;
    const int n0  = (swz % nbn) << 7;

    const unsigned short* Ag = A + (size_t)m0 * K;
    const unsigned short* Bg = B + (size_t)n0 * K;

    // staging geometry: 6 units of 8 KiB (A: 4 x 64 rows, B: 2 x 64 rows).
    // LDS phys = unit*8192 + tid*16 (linear); logical = phys ^ ((row&7)<<4).
    int srow[6], scol[6];
#pragma unroll
    for (int u = 0; u < 6; ++u) {
        const int p  = ((u < 4 ? u : u - 4) << 13) + tid * 16;
        const int l2 = p ^ (((p >> 7) & 7) << 4);
        srow[u] = l2 >> 7;
        scol[u] = (l2 & 127) >> 1;
    }

    f32x4 acc[4][4];
#pragma unroll
    for (int i = 0; i < 4; ++i)
#pragma unroll
        for (int j = 0; j < 4; ++j) acc[i][j] = f32x4{0.f, 0.f, 0.f, 0.f};

    const int NT = K >> 6;

#define STAGE_TILE(kt, s)                                                            \
    {                                                                                \
        char* plane = lds + (s) * 49152;                                             \
        const int k0 = (kt) << 6;                                                    \
        _Pragma("unroll")                                                            \
        for (int u = 0; u < 4; ++u)                                                  \
            stage16(Ag + (size_t)srow[u] * K + k0 + scol[u],                         \
                    plane + (u << 13) + tid * 16);                                   \
        _Pragma("unroll")                                                            \
        for (int u = 4; u < 6; ++u)                                                  \
            stage16(Bg + (size_t)srow[u] * K + k0 + scol[u],                         \
                    plane + 32768 + ((u - 4) << 13) + tid * 16);                     \
    }

    // prologue: tile 0 -> slot 0
    STAGE_TILE(0, 0)
    asm volatile("s_waitcnt vmcnt(0)" ::: "memory");
    __builtin_amdgcn_s_barrier();

    for (int t = 0; t < NT; ++t) {
        const int s = t & 1;
        const char* pa = lds + s * 49152;
        const char* pb = pa + 32768;

#pragma unroll
        for (int q = 0; q < 4; ++q) {
            const int mi2 = q >> 1, ni2 = q & 1;

            // ---- ds_read quadrant fragments (swizzled) ----
            bf16x8 af[2][2], bfr[2][2];
#pragma unroll
            for (int mi = 0; mi < 2; ++mi) {
                const int ra = wr * 64 + (mi2 * 2 + mi) * 16 + lr;
                const int xo = (ra & 7) << 4;
#pragma unroll
                for (int ks = 0; ks < 2; ++ks)
                    af[mi][ks] = *(const bf16x8*)(pa + ((ra * 128 + ks * 64 + lg * 16) ^ xo));
            }
#pragma unroll
            for (int ni = 0; ni < 2; ++ni) {
                const int rb = wc * 64 + (ni2 * 2 + ni) * 16 + lr;
                const int xo = (rb & 7) << 4;
#pragma unroll
                for (int ks = 0; ks < 2; ++ks)
                    bfr[ni][ks] = *(const bf16x8*)(pb + ((rb * 128 + ks * 64 + lg * 16) ^ xo));
            }

            // ---- burst-stage next tile (phase 0 only: max latency headroom) ----
            if (q == 0 && t + 1 < NT) STAGE_TILE(t + 1, s ^ 1)

            __builtin_amdgcn_s_barrier();
            asm volatile("s_waitcnt lgkmcnt(0)" ::: "memory");
            __builtin_amdgcn_sched_barrier(0);

            __builtin_amdgcn_s_setprio(1);
#pragma unroll
            for (int mi = 0; mi < 2; ++mi)
#pragma unroll
                for (int ni = 0; ni < 2; ++ni)
#pragma unroll
                    for (int ks = 0; ks < 2; ++ks)
                        acc[mi2 * 2 + mi][ni2 * 2 + ni] =
                            __builtin_amdgcn_mfma_f32_16x16x32_bf16(
                                af[mi][ks], bfr[ni][ks],
                                acc[mi2 * 2 + mi][ni2 * 2 + ni], 0, 0, 0);
            __builtin_amdgcn_s_setprio(0);

            if (q == 3)
                asm volatile("s_waitcnt vmcnt(0)" ::: "memory");  // next tile landed
            __builtin_amdgcn_s_barrier();
        }
    }
#undef STAGE_TILE

    // ---- epilogue ----
#pragma unroll
    for (int mi = 0; mi < 4; ++mi)
#pragma unroll
        for (int ni = 0; ni < 4; ++ni) {
            const int row = m0 + wr * 64 + mi * 16 + lg * 4;
            const int col = n0 + wc * 64 + ni * 16 + lr;
            float* cp = C + (size_t)row * N + col;
#pragma unroll
            for (int r = 0; r < 4; ++r) cp[(size_t)r * N] = acc[mi][ni][r];
        }
}

// ---------- per-head LayerNorm on q/k segments of Y, writes bf16 ----------
__global__ __launch_bounds__(256)
void ln_qk(const float* __restrict__ Y,
           const float* __restrict__ qg, const float* __restrict__ qb,
           const float* __restrict__ kg, const float* __restrict__ kb,
           unsigned short* __restrict__ Q, unsigned short* __restrict__ Kc)
{
    const int seg = blockIdx.x * 4 + (threadIdx.x >> 6);
    const int l = threadIdx.x & 63;
    const int s = seg / 40;
    const int hh = seg - s * 40;

    const float* y = Y + (size_t)s * NQKV + hh * 128;
    float2 v = *(const float2*)(y + l * 2);
    float sum = v.x + v.y;
    float sq  = v.x * v.x + v.y * v.y;
#pragma unroll
    for (int d = 1; d < 64; d <<= 1) {
        sum += __shfl_xor(sum, d);
        sq  += __shfl_xor(sq, d);
    }
    const float mu  = sum * (1.f / 128.f);
    const float var = sq * (1.f / 128.f) - mu * mu;
    const float rs  = rsqrtf(var + 1e-6f);

    const float* g = (hh < 32) ? qg : kg;
    const float* b = (hh < 32) ? qb : kb;
    // fold 1/sqrt(128)*log2(e) into the q-head LN output
    const float c = (hh < 32) ? (0.08838834764831845f * 1.4426950408889634f) : 1.0f;
    const float g0 = g[l * 2], g1 = g[l * 2 + 1];
    const float b0 = b[l * 2], b1 = b[l * 2 + 1];
    const unsigned short o0 = f2bfb(((v.x - mu) * rs * g0 + b0) * c);
    const unsigned short o1 = f2bfb(((v.y - mu) * rs * g1 + b1) * c);
    const unsigned pack = (unsigned)o0 | ((unsigned)o1 << 16);

    if (hh < 32) {
        unsigned* dst = (unsigned*)(Q + ((size_t)hh * SEQ + s) * 128 + l * 2);
        *dst = pack;
    } else {
        unsigned* dst = (unsigned*)(Kc + ((size_t)(hh - 32) * SEQ + s) * 128 + l * 2);
        *dst = pack;
    }
}

// ---------- V transpose: Y v-columns -> Vt[8][128][SEQ] bf16 ----------
__global__ __launch_bounds__(256)
void v_transpose(const float* __restrict__ Y, unsigned short* __restrict__ Vt)
{
    __shared__ unsigned short t[64][132];
    const int h  = blockIdx.x;
    const int s0 = blockIdx.y << 6;
    const int tid = threadIdx.x;
    const float* y = Y + (size_t)s0 * NQKV + 5120 + h * 128;

#pragma unroll
    for (int p = 0; p < 16; ++p) {
        const int idx = p * 512 + tid * 2;
        const int s = idx >> 7, d = idx & 127;
        float2 v = *(const float2*)(y + (size_t)s * NQKV + d);
        t[s][d]     = f2bfb(v.x);
        t[s][d + 1] = f2bfb(v.y);
    }
    __syncthreads();
    unsigned short* out = Vt + (size_t)h * 128 * SEQ + s0;
#pragma unroll
    for (int p = 0; p < 16; ++p) {
        const int idx = p * 512 + tid * 2;
        const int d = idx >> 6, sp = idx & 63;
        unsigned pack = (unsigned)t[sp][d] | ((unsigned)t[sp + 1][d] << 16);
        *(unsigned*)(out + (size_t)d * SEQ + sp) = pack;
    }
}

// ---------- causal GQA flash attention, swapped-operand + LDS-staged K/V ----------
__global__ __launch_bounds__(256, 2)
void attn(const unsigned short* __restrict__ Qb, const unsigned short* __restrict__ Kb,
          const unsigned short* __restrict__ Vt, unsigned short* __restrict__ Ob)
{
    __shared__ __align__(16) unsigned short Kl[2][64 * 128];   // [kv][d], 16KB each
    __shared__ __align__(16) unsigned short Vl[2][128 * 64];   // [d][kv], 16KB each

    const int h   = blockIdx.x;
    const int qt  = 15 - blockIdx.y;        // heavy q-tiles first
    const int kvh = h >> 2;
    const int tid = threadIdx.x;
    const int w   = tid >> 6;
    const int l   = tid & 63;
    const int lq  = l & 31;                 // this lane's q (within wave)
    const int hi  = l >> 5;
    const int q0  = qt << 7;
    const int wq  = q0 + (w << 5);          // wave's q base
    const int qrow = wq + lq;

    const unsigned short* Qh = Qb + ((size_t)h * SEQ + wq) * 128;
    const unsigned short* Kh = Kb + (size_t)kvh * SEQ * 128;
    const unsigned short* Vh = Vt + (size_t)kvh * 128 * SEQ;

    int koff[4], voff[4];
#pragma unroll
    for (int p = 0; p < 4; ++p) {
        const int c  = p * 256 + tid;
        const int kr = c >> 4, kc = c & 15;
        koff[p] = kr * 128 + ((kc ^ (kr & 7)) << 3);
        const int vr = c >> 3, vc = c & 7;
        voff[p] = vr * SEQ + ((vc ^ (vr & 7)) << 3);
    }
    const int dstb = w << 10;

    bf16x8 qf[8];
#pragma unroll
    for (int ks = 0; ks < 8; ++ks)
        qf[ks] = *(const bf16x8*)(Qh + lq * 128 + ks * 16 + hi * 8);

    f32x16 o0_ = {0}, o1_ = {0}, o2_ = {0}, o3_ = {0};
    float m = -1.0e30f, lsum = 0.f;

    const int nt = (q0 + 128) >> 6;
    const int sw = (lq & 7) << 4;

#pragma unroll
    for (int p = 0; p < 4; ++p)
        stage16(Kh + koff[p], (char*)Kl[0] + p * 4096 + dstb);
#pragma unroll
    for (int p = 0; p < 4; ++p)
        stage16(Vh + voff[p], (char*)Vl[0] + p * 4096 + dstb);
    __syncthreads();

    int buf = 0;
    for (int t = 0; t < nt; ++t) {
        const int kv0 = t << 6;

        if (t + 1 < nt) {
            const int kvn = kv0 + 64;
#pragma unroll
            for (int p = 0; p < 4; ++p)
                stage16(Kh + (size_t)kvn * 128 + koff[p], (char*)(Kl[buf ^ 1]) + p * 4096 + dstb);
#pragma unroll
            for (int p = 0; p < 4; ++p)
                stage16(Vh + kvn + voff[p], (char*)(Vl[buf ^ 1]) + p * 4096 + dstb);
        }

        if (kv0 <= wq + 31) {
            const char* Kb0 = (const char*)(Kl[buf]) + lq * 256;
            const char* Kb1 = (const char*)(Kl[buf]) + (lq + 32) * 256;
            bf16x8 kf0[8], kf1[8];
#pragma unroll
            for (int ks = 0; ks < 8; ++ks) {
                const int cb = (ks * 32 + hi * 16) ^ sw;
                kf0[ks] = *(const bf16x8*)(Kb0 + cb);
                kf1[ks] = *(const bf16x8*)(Kb1 + cb);
            }
            f32x16 s0 = {0}, s1 = {0};
            __builtin_amdgcn_s_setprio(1);
#pragma unroll
            for (int ks = 0; ks < 8; ++ks) {
                s0 = __builtin_amdgcn_mfma_f32_32x32x16_bf16(kf0[ks], qf[ks], s0, 0, 0, 0);
                s1 = __builtin_amdgcn_mfma_f32_32x32x16_bf16(kf1[ks], qf[ks], s1, 0, 0, 0);
            }
            __builtin_amdgcn_s_setprio(0);

            if (kv0 + 63 > wq) {
#pragma unroll
                for (int r = 0; r < 16; ++r) {
                    const int kvl = (r & 3) + 8 * (r >> 2) + 4 * hi;
                    if (kv0 + kvl > qrow)      s0[r] = -1.0e30f;
                    if (kv0 + 32 + kvl > qrow) s1[r] = -1.0e30f;
                }
            }

            float m8[8];
#pragma unroll
            for (int i = 0; i < 8; ++i)
                m8[i] = fmaxf(fmaxf(s0[i], s0[i + 8]), fmaxf(s1[i], s1[i + 8]));
#pragma unroll
            for (int i = 0; i < 4; ++i) m8[i] = fmaxf(m8[i], m8[i + 4]);
            float pm = fmaxf(fmaxf(m8[0], m8[1]), fmaxf(m8[2], m8[3]));
            pm = fmaxf(pm, __shfl_xor(pm, 32));

            if (!__all(pm - m <= 8.0f)) {
                const float mn = fmaxf(m, pm);
                const float al = exp2_fast(m - mn);
                lsum *= al;
#pragma unroll
                for (int r = 0; r < 16; ++r) { o0_[r] *= al; o1_[r] *= al; o2_[r] *= al; o3_[r] *= al; }
                m = mn;
            }

#pragma unroll
            for (int r = 0; r < 16; ++r) s0[r] = exp2_fast(s0[r] - m);
#pragma unroll
            for (int r = 0; r < 16; ++r) s1[r] = exp2_fast(s1[r] - m);
            float a8[8];
#pragma unroll
            for (int i = 0; i < 8; ++i)
                a8[i] = (s0[i] + s0[i + 8]) + (s1[i] + s1[i + 8]);
#pragma unroll
            for (int i = 0; i < 4; ++i) a8[i] += a8[i + 4];
            float rs = (a8[0] + a8[1]) + (a8[2] + a8[3]);
            rs += __shfl_xor(rs, 32);
            lsum += rs;

            unsigned pw0[2][4], pw1[2][4];
#pragma unroll
            for (int u = 0; u < 4; ++u) {
                pw0[0][u] = cvt_pk_bf16(s0[u * 4 + 0], s0[u * 4 + 1]);
                pw1[0][u] = cvt_pk_bf16(s0[u * 4 + 2], s0[u * 4 + 3]);
                pw0[1][u] = cvt_pk_bf16(s1[u * 4 + 0], s1[u * 4 + 1]);
                pw1[1][u] = cvt_pk_bf16(s1[u * 4 + 2], s1[u * 4 + 3]);
            }

            const char* Vb = (const char*)(Vl[buf]);
#pragma unroll
            for (int ksg = 0; ksg < 4; ++ksg) {
                const int b  = ksg >> 1;
                const int ks = ksg & 1;
                const unsigned a0 = pw0[b][2 * ks],     a1 = pw1[b][2 * ks];
                const unsigned b0 = pw0[b][2 * ks + 1], b1 = pw1[b][2 * ks + 1];
                const unsigned sa0 = __shfl_xor(a0, 32);
                const unsigned sb0 = __shfl_xor(b0, 32);
                const unsigned sa1 = __shfl_xor(a1, 32);
                const unsigned sb1 = __shfl_xor(b1, 32);
                union { unsigned wrd[4]; bf16x8 v; } pb;
                pb.wrd[0] = hi ? sb0 : a0;
                pb.wrd[1] = hi ? sb1 : a1;
                pb.wrd[2] = hi ? b0  : sa0;
                pb.wrd[3] = hi ? b1  : sa1;

                const int cb = (ksg * 32 + hi * 16) ^ sw;
                bf16x8 vf0 = *(const bf16x8*)(Vb + (lq)       * 128 + cb);
                bf16x8 vf1 = *(const bf16x8*)(Vb + (lq + 32)  * 128 + cb);
                bf16x8 vf2 = *(const bf16x8*)(Vb + (lq + 64)  * 128 + cb);
                bf16x8 vf3 = *(const bf16x8*)(Vb + (lq + 96)  * 128 + cb);
                __builtin_amdgcn_s_setprio(1);
                o0_ = __builtin_amdgcn_mfma_f32_32x32x16_bf16(vf0, pb.v, o0_, 0, 0, 0);
                o1_ = __builtin_amdgcn_mfma_f32_32x32x16_bf16(vf1, pb.v, o1_, 0, 0, 0);
                o2_ = __builtin_amdgcn_mfma_f32_32x32x16_bf16(vf2, pb.v, o2_, 0, 0, 0);
                o3_ = __builtin_amdgcn_mfma_f32_32x32x16_bf16(vf3, pb.v, o3_, 0, 0, 0);
                __builtin_amdgcn_s_setprio(0);
            }
        }

        __syncthreads();
        buf ^= 1;
    }

    const float inv = 1.0f / lsum;
    unsigned short* orow = Ob + (size_t)qrow * DM + h * 128;
#pragma unroll
    for (int r = 0; r < 16; r += 2) {
        const int doff = 8 * (r >> 2) + 4 * hi + (r & 3);
        *(unsigned*)(orow + 0  + doff) = cvt_pk_bf16(o0_[r] * inv, o0_[r + 1] * inv);
        *(unsigned*)(orow + 32 + doff) = cvt_pk_bf16(o1_[r] * inv, o1_[r + 1] * inv);
        *(unsigned*)(orow + 64 + doff) = cvt_pk_bf16(o2_[r] * inv, o2_[r + 1] * inv);
        *(unsigned*)(orow + 96 + doff) = cvt_pk_bf16(o3_[r] * inv, o3_[r + 1] * inv);
    }
}

// ---------- launch ----------
extern "C" void kernel_launch(void* const* d_in, const int* in_sizes, int n_in,
                              void* d_out, int out_size, void* d_ws, size_t ws_size,
                              hipStream_t stream)
{
    const float* x  = (const float*)d_in[0];
    const float* Wq = (const float*)d_in[3];
    const float* Wk = (const float*)d_in[4];
    const float* Wv = (const float*)d_in[5];
    const float* Wo = (const float*)d_in[6];
    const float* qg = (const float*)d_in[7];
    const float* qb = (const float*)d_in[8];
    const float* kg = (const float*)d_in[9];
    const float* kb = (const float*)d_in[10];
    float* out = (float*)d_out;

    char* ws = (char*)d_ws;
    unsigned short* xb   = (unsigned short*)(ws);
    unsigned short* wqkv = (unsigned short*)(ws + 16777216);
    unsigned short* wo   = (unsigned short*)(ws + 67108864);
    float*          y    = (float*)        (ws + 100663296);
    unsigned short* qbuf = (unsigned short*)(ws + 150994944);
    unsigned short* kbuf = (unsigned short*)(ws + 167772160);
    unsigned short* vtb  = (unsigned short*)(ws + 171966464);
    unsigned short* ob   = (unsigned short*)(ws + 176160768);

    // 1) fp32 -> bf16 conversions
    {
        int n4 = (SEQ * DM) / 4;
        cvt_bf16<<<2048, 256, 0, stream>>>((const float4*)x, (ushort4*)xb, n4);
        n4 = (NQH * DK * DM) / 4;
        cvt_bf16<<<2048, 256, 0, stream>>>((const float4*)Wq, (ushort4*)wqkv, n4);
        n4 = (NKVH * DK * DM) / 4;
        cvt_bf16<<<2048, 256, 0, stream>>>((const float4*)Wk, (ushort4*)(wqkv + 16777216), n4);
        cvt_bf16<<<2048, 256, 0, stream>>>((const float4*)Wv, (ushort4*)(wqkv + 20971520), n4);
        n4 = (DM * DM) / 4;
        cvt_bf16<<<2048, 256, 0, stream>>>((const float4*)Wo, (ushort4*)wo, n4);
    }

    // 2) fused QKV projection: Y[2048][6144] = xb @ wqkv^T  (384 blocks)
    gemm256<<<(SEQ / 256) * (NQKV / 128), 512, 0, stream>>>(xb, wqkv, y, SEQ, NQKV, DM);

    // 3) per-head LN on q,k -> bf16 head-major buffers (q pre-scaled)
    ln_qk<<<(SEQ * 40) / 4, 256, 0, stream>>>(y, qg, qb, kg, kb, qbuf, kbuf);

    // 4) V transpose -> Vt[8][128][2048]
    v_transpose<<<dim3(NKVH, SEQ / 64), 256, 0, stream>>>(y, vtb);

    // 5) causal GQA flash attention -> ob[2048][4096]
    attn<<<dim3(NQH, SEQ / 128), 256, 0, stream>>>(qbuf, kbuf, vtb, ob);

    // 6) output projection: out = ob @ wo^T (fp32 out, 256 blocks)
    gemm256<<<(SEQ / 256) * (DM / 128), 512, 0, stream>>>(ob, wo, out, SEQ, DM, DM);
}

// Round 9
// 531.461 us; speedup vs baseline: 1.1065x; 1.1065x over previous
//
#include <hip/hip_runtime.h>
#include <stdint.h>

typedef short bf16x8 __attribute__((ext_vector_type(8)));
typedef float f32x4 __attribute__((ext_vector_type(4)));
typedef float f32x16 __attribute__((ext_vector_type(16)));

#define SEQ     2048
#define DM      4096
#define NQH     32
#define NKVH    8
#define DK      128
#define NQKV    6144   // 4096 q + 1024 k + 1024 v

// ---------- helpers ----------
__device__ __forceinline__ unsigned short f2bfb(float f) {
    union { float f; unsigned u; } x; x.f = f;
    unsigned r = x.u + 0x7FFFu + ((x.u >> 16) & 1u);   // RNE
    return (unsigned short)(r >> 16);
}

__device__ __forceinline__ unsigned cvt_pk_bf16(float a, float b) {
    unsigned r;
    asm("v_cvt_pk_bf16_f32 %0, %1, %2" : "=v"(r) : "v"(a), "v"(b));
    return r;
}

#if __has_builtin(__builtin_amdgcn_exp2f)
__device__ __forceinline__ float exp2_fast(float x) { return __builtin_amdgcn_exp2f(x); }
#else
__device__ __forceinline__ float exp2_fast(float x) { return exp2f(x); }
#endif

__device__ __forceinline__ void stage16(const void* g, void* l) {
    __builtin_amdgcn_global_load_lds(
        (const __attribute__((address_space(1))) void*)g,
        (__attribute__((address_space(3))) void*)l,
        16, 0, 0);
}

// ---------- fp32 -> bf16 conversion (vectorized, grid-stride) ----------
__global__ __launch_bounds__(256)
void cvt_bf16(const float4* __restrict__ src, ushort4* __restrict__ dst, int n4) {
    int i = blockIdx.x * 256 + threadIdx.x;
    const int stride = gridDim.x * 256;
    for (; i < n4; i += stride) {
        float4 f = src[i];
        ushort4 u;
        u.x = f2bfb(f.x); u.y = f2bfb(f.y); u.z = f2bfb(f.z); u.w = f2bfb(f.w);
        dst[i] = u;
    }
}

// ---------- GEMM, 4-buffer counted-vmcnt pipeline ----------
// C[M][N] = A[M][K](bf16) * B[N][K](bf16)^T, fp32 out.
// BM=BN=256, BK=32. 512 threads = 8 waves (2M x 4N), per-wave 128x64 output.
// LDS: 4 buffers x (A[256][32] + B[256][32]) = 128 KiB. Prefetch distance 3.
// Swizzle: 16B chunk index ^= (row>>1)&3, applied on global SOURCE at staging
// (linear LDS dest, rule #21) and on ds_read addresses -> 2 lanes/bank (free).
// Steady state: vmcnt(8) per tile (2 tiles always in flight), ONE barrier/tile.
__global__ __launch_bounds__(512, 1)
void gemm_p4(const unsigned short* __restrict__ A, const unsigned short* __restrict__ B,
             float* __restrict__ C, int M, int N, int K)
{
    __shared__ __align__(16) char lds[4][32768];

    const int tid = threadIdx.x;
    const int w   = tid >> 6;
    const int l   = tid & 63;
    const int lr  = l & 15;
    const int lg  = l >> 4;
    const int wr  = w >> 2;          // 0..1 -> M offset wr*128
    const int wc  = w & 3;           // 0..3 -> N offset wc*64

    // XCD-chunked block swizzle (nwg % 8 == 0 for both our GEMMs)
    const int nbn = N >> 8;
    const int qz  = gridDim.x >> 3;
    const int id  = blockIdx.x;
    const int swz = (id & 7) * qz + (id >> 3);
    const int m0  = (swz / nbn) << 8;
    const int n0  = (swz % nbn) << 8;

    const unsigned short* Ag = A + (size_t)m0 * K;
    const unsigned short* Bg = B + (size_t)n0 * K;

    // staging geometry: per buffer A=16KB (2 units of 8KB), B same.
    // phys byte p = u*8192 + tid*16 -> row = u*128 + tid/4, phys chunk = tid&3,
    // source chunk = phys ^ ((row>>1)&3) = (tid&3) ^ ((tid>>3)&3) (both units).
    const int    srow  = tid >> 2;
    const int    scs   = (tid & 3) ^ ((tid >> 3) & 3);
    const size_t aoff0 = (size_t)srow * K + scs * 8;
    const size_t aoff1 = (size_t)(srow + 128) * K + scs * 8;
    const int    dsto  = tid * 16;

    // frag LDS byte offsets (tile-invariant): logical chunk lg at phys lg^((row>>1)&3)
    int offA[8], offB[4];
#pragma unroll
    for (int mi = 0; mi < 8; ++mi) {
        const int row = wr * 128 + mi * 16 + lr;
        offA[mi] = row * 64 + ((lg ^ ((row >> 1) & 3)) << 4);
    }
#pragma unroll
    for (int ni = 0; ni < 4; ++ni) {
        const int row = wc * 64 + ni * 16 + lr;
        offB[ni] = 16384 + row * 64 + ((lg ^ ((row >> 1) & 3)) << 4);
    }

    f32x4 acc[8][4];
#pragma unroll
    for (int i = 0; i < 8; ++i)
#pragma unroll
        for (int j = 0; j < 4; ++j) acc[i][j] = f32x4{0.f, 0.f, 0.f, 0.f};

    const int NT = K >> 5;

#define STG(t)                                                   \
    {                                                            \
        char* pl = lds[(t) & 3];                                 \
        const int k0 = (t) << 5;                                 \
        stage16(Ag + aoff0 + k0, pl + dsto);                     \
        stage16(Ag + aoff1 + k0, pl + 8192  + dsto);             \
        stage16(Bg + aoff0 + k0, pl + 16384 + dsto);             \
        stage16(Bg + aoff1 + k0, pl + 24576 + dsto);             \
    }

    // prologue: tiles 0,1,2 in flight; wait tile 0 only
    STG(0) STG(1) STG(2)
    asm volatile("s_waitcnt vmcnt(8)" ::: "memory");
    __builtin_amdgcn_s_barrier();

    for (int t = 0; t < NT; ++t) {
        const char* pl = lds[t & 3];

        bf16x8 af[8], bfv[4];
#pragma unroll
        for (int mi = 0; mi < 8; ++mi) af[mi] = *(const bf16x8*)(pl + offA[mi]);
#pragma unroll
        for (int ni = 0; ni < 4; ++ni) bfv[ni] = *(const bf16x8*)(pl + offB[ni]);

        if (t + 3 < NT) STG(t + 3)    // targets buf[(t-1)&3]: reads done last iter

        __builtin_amdgcn_s_setprio(1);
#pragma unroll
        for (int mi = 0; mi < 8; ++mi)
#pragma unroll
            for (int ni = 0; ni < 4; ++ni)
                acc[mi][ni] = __builtin_amdgcn_mfma_f32_16x16x32_bf16(
                    af[mi], bfv[ni], acc[mi][ni], 0, 0, 0);
        __builtin_amdgcn_s_setprio(0);

        // wait tile t+1 landed; keep t+2,t+3 in flight (counted, never 0 in steady)
        if (t + 3 < NT)      { asm volatile("s_waitcnt vmcnt(8)" ::: "memory"); }
        else if (t + 2 < NT) { asm volatile("s_waitcnt vmcnt(4)" ::: "memory"); }
        else if (t + 1 < NT) { asm volatile("s_waitcnt vmcnt(0)" ::: "memory"); }
        if (t + 1 < NT) __builtin_amdgcn_s_barrier();
    }
#undef STG

    // ---- epilogue ----
#pragma unroll
    for (int mi = 0; mi < 8; ++mi)
#pragma unroll
        for (int ni = 0; ni < 4; ++ni) {
            const int row = m0 + wr * 128 + mi * 16 + lg * 4;
            const int col = n0 + wc * 64 + ni * 16 + lr;
            float* cp = C + (size_t)row * N + col;
#pragma unroll
            for (int r = 0; r < 4; ++r) cp[(size_t)r * N] = acc[mi][ni][r];
        }
}

// ---------- per-head LayerNorm on q/k segments of Y, writes bf16 ----------
__global__ __launch_bounds__(256)
void ln_qk(const float* __restrict__ Y,
           const float* __restrict__ qg, const float* __restrict__ qb,
           const float* __restrict__ kg, const float* __restrict__ kb,
           unsigned short* __restrict__ Q, unsigned short* __restrict__ Kc)
{
    const int seg = blockIdx.x * 4 + (threadIdx.x >> 6);
    const int l = threadIdx.x & 63;
    const int s = seg / 40;
    const int hh = seg - s * 40;

    const float* y = Y + (size_t)s * NQKV + hh * 128;
    float2 v = *(const float2*)(y + l * 2);
    float sum = v.x + v.y;
    float sq  = v.x * v.x + v.y * v.y;
#pragma unroll
    for (int d = 1; d < 64; d <<= 1) {
        sum += __shfl_xor(sum, d);
        sq  += __shfl_xor(sq, d);
    }
    const float mu  = sum * (1.f / 128.f);
    const float var = sq * (1.f / 128.f) - mu * mu;
    const float rs  = rsqrtf(var + 1e-6f);

    const float* g = (hh < 32) ? qg : kg;
    const float* b = (hh < 32) ? qb : kb;
    // fold 1/sqrt(128)*log2(e) into the q-head LN output
    const float c = (hh < 32) ? (0.08838834764831845f * 1.4426950408889634f) : 1.0f;
    const float g0 = g[l * 2], g1 = g[l * 2 + 1];
    const float b0 = b[l * 2], b1 = b[l * 2 + 1];
    const unsigned short o0 = f2bfb(((v.x - mu) * rs * g0 + b0) * c);
    const unsigned short o1 = f2bfb(((v.y - mu) * rs * g1 + b1) * c);
    const unsigned pack = (unsigned)o0 | ((unsigned)o1 << 16);

    if (hh < 32) {
        unsigned* dst = (unsigned*)(Q + ((size_t)hh * SEQ + s) * 128 + l * 2);
        *dst = pack;
    } else {
        unsigned* dst = (unsigned*)(Kc + ((size_t)(hh - 32) * SEQ + s) * 128 + l * 2);
        *dst = pack;
    }
}

// ---------- V transpose: Y v-columns -> Vt[8][128][SEQ] bf16 ----------
__global__ __launch_bounds__(256)
void v_transpose(const float* __restrict__ Y, unsigned short* __restrict__ Vt)
{
    __shared__ unsigned short t[64][132];
    const int h  = blockIdx.x;
    const int s0 = blockIdx.y << 6;
    const int tid = threadIdx.x;
    const float* y = Y + (size_t)s0 * NQKV + 5120 + h * 128;

#pragma unroll
    for (int p = 0; p < 16; ++p) {
        const int idx = p * 512 + tid * 2;
        const int s = idx >> 7, d = idx & 127;
        float2 v = *(const float2*)(y + (size_t)s * NQKV + d);
        t[s][d]     = f2bfb(v.x);
        t[s][d + 1] = f2bfb(v.y);
    }
    __syncthreads();
    unsigned short* out = Vt + (size_t)h * 128 * SEQ + s0;
#pragma unroll
    for (int p = 0; p < 16; ++p) {
        const int idx = p * 512 + tid * 2;
        const int d = idx >> 6, sp = idx & 63;
        unsigned pack = (unsigned)t[sp][d] | ((unsigned)t[sp + 1][d] << 16);
        *(unsigned*)(out + (size_t)d * SEQ + sp) = pack;
    }
}

// ---------- causal GQA flash attention, swapped-operand + LDS-staged K/V ----------
__global__ __launch_bounds__(256, 2)
void attn(const unsigned short* __restrict__ Qb, const unsigned short* __restrict__ Kb,
          const unsigned short* __restrict__ Vt, unsigned short* __restrict__ Ob)
{
    __shared__ __align__(16) unsigned short Kl[2][64 * 128];   // [kv][d], 16KB each
    __shared__ __align__(16) unsigned short Vl[2][128 * 64];   // [d][kv], 16KB each

    const int h   = blockIdx.x;
    const int qt  = 15 - blockIdx.y;        // heavy q-tiles first
    const int kvh = h >> 2;
    const int tid = threadIdx.x;
    const int w   = tid >> 6;
    const int l   = tid & 63;
    const int lq  = l & 31;                 // this lane's q (within wave)
    const int hi  = l >> 5;
    const int q0  = qt << 7;
    const int wq  = q0 + (w << 5);          // wave's q base
    const int qrow = wq + lq;

    const unsigned short* Qh = Qb + ((size_t)h * SEQ + wq) * 128;
    const unsigned short* Kh = Kb + (size_t)kvh * SEQ * 128;
    const unsigned short* Vh = Vt + (size_t)kvh * 128 * SEQ;

    int koff[4], voff[4];
#pragma unroll
    for (int p = 0; p < 4; ++p) {
        const int c  = p * 256 + tid;
        const int kr = c >> 4, kc = c & 15;
        koff[p] = kr * 128 + ((kc ^ (kr & 7)) << 3);
        const int vr = c >> 3, vc = c & 7;
        voff[p] = vr * SEQ + ((vc ^ (vr & 7)) << 3);
    }
    const int dstb = w << 10;

    bf16x8 qf[8];
#pragma unroll
    for (int ks = 0; ks < 8; ++ks)
        qf[ks] = *(const bf16x8*)(Qh + lq * 128 + ks * 16 + hi * 8);

    f32x16 o0_ = {0}, o1_ = {0}, o2_ = {0}, o3_ = {0};
    float m = -1.0e30f, lsum = 0.f;

    const int nt = (q0 + 128) >> 6;
    const int sw = (lq & 7) << 4;

#pragma unroll
    for (int p = 0; p < 4; ++p)
        stage16(Kh + koff[p], (char*)Kl[0] + p * 4096 + dstb);
#pragma unroll
    for (int p = 0; p < 4; ++p)
        stage16(Vh + voff[p], (char*)Vl[0] + p * 4096 + dstb);
    __syncthreads();

    int buf = 0;
    for (int t = 0; t < nt; ++t) {
        const int kv0 = t << 6;

        if (t + 1 < nt) {
            const int kvn = kv0 + 64;
#pragma unroll
            for (int p = 0; p < 4; ++p)
                stage16(Kh + (size_t)kvn * 128 + koff[p], (char*)(Kl[buf ^ 1]) + p * 4096 + dstb);
#pragma unroll
            for (int p = 0; p < 4; ++p)
                stage16(Vh + kvn + voff[p], (char*)(Vl[buf ^ 1]) + p * 4096 + dstb);
        }

        if (kv0 <= wq + 31) {
            const char* Kb0 = (const char*)(Kl[buf]) + lq * 256;
            const char* Kb1 = (const char*)(Kl[buf]) + (lq + 32) * 256;
            bf16x8 kf0[8], kf1[8];
#pragma unroll
            for (int ks = 0; ks < 8; ++ks) {
                const int cb = (ks * 32 + hi * 16) ^ sw;
                kf0[ks] = *(const bf16x8*)(Kb0 + cb);
                kf1[ks] = *(const bf16x8*)(Kb1 + cb);
            }
            f32x16 s0 = {0}, s1 = {0};
            __builtin_amdgcn_s_setprio(1);
#pragma unroll
            for (int ks = 0; ks < 8; ++ks) {
                s0 = __builtin_amdgcn_mfma_f32_32x32x16_bf16(kf0[ks], qf[ks], s0, 0, 0, 0);
                s1 = __builtin_amdgcn_mfma_f32_32x32x16_bf16(kf1[ks], qf[ks], s1, 0, 0, 0);
            }
            __builtin_amdgcn_s_setprio(0);

            if (kv0 + 63 > wq) {
#pragma unroll
                for (int r = 0; r < 16; ++r) {
                    const int kvl = (r & 3) + 8 * (r >> 2) + 4 * hi;
                    if (kv0 + kvl > qrow)      s0[r] = -1.0e30f;
                    if (kv0 + 32 + kvl > qrow) s1[r] = -1.0e30f;
                }
            }

            float m8[8];
#pragma unroll
            for (int i = 0; i < 8; ++i)
                m8[i] = fmaxf(fmaxf(s0[i], s0[i + 8]), fmaxf(s1[i], s1[i + 8]));
#pragma unroll
            for (int i = 0; i < 4; ++i) m8[i] = fmaxf(m8[i], m8[i + 4]);
            float pm = fmaxf(fmaxf(m8[0], m8[1]), fmaxf(m8[2], m8[3]));
            pm = fmaxf(pm, __shfl_xor(pm, 32));

            if (!__all(pm - m <= 8.0f)) {
                const float mn = fmaxf(m, pm);
                const float al = exp2_fast(m - mn);
                lsum *= al;
#pragma unroll
                for (int r = 0; r < 16; ++r) { o0_[r] *= al; o1_[r] *= al; o2_[r] *= al; o3_[r] *= al; }
                m = mn;
            }

#pragma unroll
            for (int r = 0; r < 16; ++r) s0[r] = exp2_fast(s0[r] - m);
#pragma unroll
            for (int r = 0; r < 16; ++r) s1[r] = exp2_fast(s1[r] - m);
            float a8[8];
#pragma unroll
            for (int i = 0; i < 8; ++i)
                a8[i] = (s0[i] + s0[i + 8]) + (s1[i] + s1[i + 8]);
#pragma unroll
            for (int i = 0; i < 4; ++i) a8[i] += a8[i + 4];
            float rs = (a8[0] + a8[1]) + (a8[2] + a8[3]);
            rs += __shfl_xor(rs, 32);
            lsum += rs;

            unsigned pw0[2][4], pw1[2][4];
#pragma unroll
            for (int u = 0; u < 4; ++u) {
                pw0[0][u] = cvt_pk_bf16(s0[u * 4 + 0], s0[u * 4 + 1]);
                pw1[0][u] = cvt_pk_bf16(s0[u * 4 + 2], s0[u * 4 + 3]);
                pw0[1][u] = cvt_pk_bf16(s1[u * 4 + 0], s1[u * 4 + 1]);
                pw1[1][u] = cvt_pk_bf16(s1[u * 4 + 2], s1[u * 4 + 3]);
            }

            const char* Vb = (const char*)(Vl[buf]);
#pragma unroll
            for (int ksg = 0; ksg < 4; ++ksg) {
                const int b  = ksg >> 1;
                const int ks = ksg & 1;
                const unsigned a0 = pw0[b][2 * ks],     a1 = pw1[b][2 * ks];
                const unsigned b0 = pw0[b][2 * ks + 1], b1 = pw1[b][2 * ks + 1];
                const unsigned sa0 = __shfl_xor(a0, 32);
                const unsigned sb0 = __shfl_xor(b0, 32);
                const unsigned sa1 = __shfl_xor(a1, 32);
                const unsigned sb1 = __shfl_xor(b1, 32);
                union { unsigned wrd[4]; bf16x8 v; } pb;
                pb.wrd[0] = hi ? sb0 : a0;
                pb.wrd[1] = hi ? sb1 : a1;
                pb.wrd[2] = hi ? b0  : sa0;
                pb.wrd[3] = hi ? b1  : sa1;

                const int cb = (ksg * 32 + hi * 16) ^ sw;
                bf16x8 vf0 = *(const bf16x8*)(Vb + (lq)       * 128 + cb);
                bf16x8 vf1 = *(const bf16x8*)(Vb + (lq + 32)  * 128 + cb);
                bf16x8 vf2 = *(const bf16x8*)(Vb + (lq + 64)  * 128 + cb);
                bf16x8 vf3 = *(const bf16x8*)(Vb + (lq + 96)  * 128 + cb);
                __builtin_amdgcn_s_setprio(1);
                o0_ = __builtin_amdgcn_mfma_f32_32x32x16_bf16(vf0, pb.v, o0_, 0, 0, 0);
                o1_ = __builtin_amdgcn_mfma_f32_32x32x16_bf16(vf1, pb.v, o1_, 0, 0, 0);
                o2_ = __builtin_amdgcn_mfma_f32_32x32x16_bf16(vf2, pb.v, o2_, 0, 0, 0);
                o3_ = __builtin_amdgcn_mfma_f32_32x32x16_bf16(vf3, pb.v, o3_, 0, 0, 0);
                __builtin_amdgcn_s_setprio(0);
            }
        }

        __syncthreads();
        buf ^= 1;
    }

    const float inv = 1.0f / lsum;
    unsigned short* orow = Ob + (size_t)qrow * DM + h * 128;
#pragma unroll
    for (int r = 0; r < 16; r += 2) {
        const int doff = 8 * (r >> 2) + 4 * hi + (r & 3);
        *(unsigned*)(orow + 0  + doff) = cvt_pk_bf16(o0_[r] * inv, o0_[r + 1] * inv);
        *(unsigned*)(orow + 32 + doff) = cvt_pk_bf16(o1_[r] * inv, o1_[r + 1] * inv);
        *(unsigned*)(orow + 64 + doff) = cvt_pk_bf16(o2_[r] * inv, o2_[r + 1] * inv);
        *(unsigned*)(orow + 96 + doff) = cvt_pk_bf16(o3_[r] * inv, o3_[r + 1] * inv);
    }
}

// ---------- launch ----------
extern "C" void kernel_launch(void* const* d_in, const int* in_sizes, int n_in,
                              void* d_out, int out_size, void* d_ws, size_t ws_size,
                              hipStream_t stream)
{
    const float* x  = (const float*)d_in[0];
    const float* Wq = (const float*)d_in[3];
    const float* Wk = (const float*)d_in[4];
    const float* Wv = (const float*)d_in[5];
    const float* Wo = (const float*)d_in[6];
    const float* qg = (const float*)d_in[7];
    const float* qb = (const float*)d_in[8];
    const float* kg = (const float*)d_in[9];
    const float* kb = (const float*)d_in[10];
    float* out = (float*)d_out;

    char* ws = (char*)d_ws;
    unsigned short* xb   = (unsigned short*)(ws);
    unsigned short* wqkv = (unsigned short*)(ws + 16777216);
    unsigned short* wo   = (unsigned short*)(ws + 67108864);
    float*          y    = (float*)        (ws + 100663296);
    unsigned short* qbuf = (unsigned short*)(ws + 150994944);
    unsigned short* kbuf = (unsigned short*)(ws + 167772160);
    unsigned short* vtb  = (unsigned short*)(ws + 171966464);
    unsigned short* ob   = (unsigned short*)(ws + 176160768);

    // 1) fp32 -> bf16 conversions
    {
        int n4 = (SEQ * DM) / 4;
        cvt_bf16<<<2048, 256, 0, stream>>>((const float4*)x, (ushort4*)xb, n4);
        n4 = (NQH * DK * DM) / 4;
        cvt_bf16<<<2048, 256, 0, stream>>>((const float4*)Wq, (ushort4*)wqkv, n4);
        n4 = (NKVH * DK * DM) / 4;
        cvt_bf16<<<2048, 256, 0, stream>>>((const float4*)Wk, (ushort4*)(wqkv + 16777216), n4);
        cvt_bf16<<<2048, 256, 0, stream>>>((const float4*)Wv, (ushort4*)(wqkv + 20971520), n4);
        n4 = (DM * DM) / 4;
        cvt_bf16<<<2048, 256, 0, stream>>>((const float4*)Wo, (ushort4*)wo, n4);
    }

    // 2) fused QKV projection: Y[2048][6144] = xb @ wqkv^T  (192 blocks)
    gemm_p4<<<(SEQ / 256) * (NQKV / 256), 512, 0, stream>>>(xb, wqkv, y, SEQ, NQKV, DM);

    // 3) per-head LN on q,k -> bf16 head-major buffers (q pre-scaled)
    ln_qk<<<(SEQ * 40) / 4, 256, 0, stream>>>(y, qg, qb, kg, kb, qbuf, kbuf);

    // 4) V transpose -> Vt[8][128][2048]
    v_transpose<<<dim3(NKVH, SEQ / 64), 256, 0, stream>>>(y, vtb);

    // 5) causal GQA flash attention -> ob[2048][4096]
    attn<<<dim3(NQH, SEQ / 128), 256, 0, stream>>>(qbuf, kbuf, vtb, ob);

    // 6) output projection: out = ob @ wo^T (fp32 out, 128 blocks)
    gemm_p4<<<(SEQ / 256) * (DM / 256), 512, 0, stream>>>(ob, wo, out, SEQ, DM, DM);
}